// Round 1
// 659.107 us; speedup vs baseline: 1.0450x; 1.0450x over previous
//
#include <hip/hip_runtime.h>
#include <stdint.h>

#define TOKENS 2048
#define HIDDEN 2048
#define INTER  1408
#define NEXP   16
#define BK     64      // K-tile; LDS rows are 64 ushorts = 128 B, 8 x 16B chunks
#define MAXTILES 48    // max sum_e ceil(ne/128): 4096/128 + 16 = 48

using bf16x8 = __attribute__((ext_vector_type(8))) __bf16;
using f32x8  = __attribute__((ext_vector_type(8))) float;
using f32x4  = __attribute__((ext_vector_type(4))) float;

__device__ __forceinline__ unsigned short bf16bits(float f) {
    union { __bf16 h; unsigned short u; } cv;
    cv.h = (__bf16)f;
    return cv.u;
}

__device__ __forceinline__ void cvt_store8(const f32x8& s, unsigned short* dst) {
    bf16x8 v;
#pragma unroll
    for (int j = 0; j < 8; j++) v[j] = (__bf16)s[j];
    *(bf16x8*)dst = v;
}

// ---------------- router: logits -> sigmoid -> top2 -> expert lists; also x -> bf16 ----------------
__global__ __launch_bounds__(64) void router_kernel(
    const float* __restrict__ x, const float* __restrict__ wg,
    int* __restrict__ cnt, int* __restrict__ tok, float* __restrict__ wts,
    unsigned short* __restrict__ xbf)
{
    const int t = blockIdx.x;
    const int lane = threadIdx.x;
    float acc[NEXP];
#pragma unroll
    for (int e = 0; e < NEXP; e++) acc[e] = 0.f;
    const float* xr = x + (size_t)t * HIDDEN;
    unsigned short* xbr = xbf + (size_t)t * HIDDEN;
    for (int h = lane; h < HIDDEN; h += 64) {
        const float xv = xr[h];
        xbr[h] = bf16bits(xv);
        const float* wr = wg + (size_t)h * NEXP;
#pragma unroll
        for (int e = 0; e < NEXP; e++) acc[e] += xv * wr[e];
    }
#pragma unroll
    for (int off = 32; off > 0; off >>= 1) {
#pragma unroll
        for (int e = 0; e < NEXP; e++) acc[e] += __shfl_down(acc[e], off, 64);
    }
    if (lane == 0) {
        float s[NEXP];
#pragma unroll
        for (int e = 0; e < NEXP; e++) s[e] = 1.f / (1.f + __expf(-acc[e]));
        int i0 = 0;
#pragma unroll
        for (int e = 1; e < NEXP; e++) if (s[e] > s[i0]) i0 = e;
        int i1 = (i0 == 0) ? 1 : 0;
#pragma unroll
        for (int e = 0; e < NEXP; e++) if (e != i0 && s[e] > s[i1]) i1 = e;
        float w0 = s[i0], w1 = s[i1];
        const float inv = 1.f / (w0 + w1);
        w0 *= inv; w1 *= inv;
        const int s0 = atomicAdd(&cnt[i0], 1);
        tok[i0 * TOKENS + s0] = t * 2;
        wts[i0 * TOKENS + s0] = w0;
        const int s1 = atomicAdd(&cnt[i1], 1);
        tok[i1 * TOKENS + s1] = t * 2 + 1;
        wts[i1 * TOKENS + s1] = w1;
    }
}

// ---------------- schedule: compact (expert, m-tile) list so every gemm block has work -------------
__global__ __launch_bounds__(64) void schedule_kernel(const int* __restrict__ cnt,
                                                      int* __restrict__ tiles)
{
    if (threadIdx.x == 0) {
        int p = 0;
        for (int e = 0; e < NEXP; e++) {
            const int nt = (cnt[e] + 127) >> 7;
            for (int m = 0; m < nt; m++) {
                if (p < MAXTILES) tiles[p] = (e << 16) | m;
                p++;
            }
        }
        for (; p < MAXTILES; p++) tiles[p] = -1;
    }
}

// B prefetch: 8 strided fp32 loads into a named f32x8 (no arrays, no lambda -> no scratch)
#define LOADVEC8(dstv, baseptr, koff, ldstride)                         \
    do {                                                                \
        const float* _s = (baseptr) + (size_t)(koff) * (ldstride);      \
        _Pragma("unroll")                                               \
        for (int _j = 0; _j < 8; _j++) dstv[_j] = _s[(size_t)_j * (ldstride)]; \
    } while (0)

// A prefetch / stage from regs
#define G_LOADA(k)                                                      \
    do {                                                                \
        a0 = *(const uint4*)(asrc0 + (k));                              \
        a1 = *(const uint4*)(asrc1 + (k));                              \
        a2 = *(const uint4*)(asrc2 + (k));                              \
        a3 = *(const uint4*)(asrc3 + (k));                              \
    } while (0)
#define G_STAGEA()                                                      \
    do {                                                                \
        *(uint4*)adst0 = a0; *(uint4*)adst1 = a1;                       \
        *(uint4*)adst2 = a2; *(uint4*)adst3 = a3;                       \
    } while (0)

// barrier1: LDS writes must be visible; do NOT drain vmcnt (prefetches stay in flight)
#define FENCE_LGKM_BAR()                                                \
    do {                                                                \
        asm volatile("s_waitcnt lgkmcnt(0)" ::: "memory");              \
        __builtin_amdgcn_s_barrier();                                   \
    } while (0)
// barrier2: pin ds_reads above / next-step ds_writes below; no waitcnt at all
#define FENCE_BAR2()                                                    \
    do {                                                                \
        asm volatile("" ::: "memory");                                  \
        __builtin_amdgcn_s_barrier();                                   \
        asm volatile("" ::: "memory");                                  \
    } while (0)

// ---------------- gemm1: h = silu(Xe @ Wg) * (Xe @ Wu), bf16 out ----------------
// grid: (INTER/64, MAXTILES), block 256. BM=128 BN=64 BK=64.
// K-loop: raw barriers + counted vmcnt (compiler-tracked), depth-2 B reg prefetch, depth-1 A.
__global__ __launch_bounds__(256, 2) void gemm1_kernel(
    const unsigned short* __restrict__ xbf, const float* __restrict__ wgp,
    const float* __restrict__ wup, const int* __restrict__ cnt,
    const int* __restrict__ tok, const int* __restrict__ tiles,
    unsigned short* __restrict__ hbuf)
{
    const int te = tiles[blockIdx.y];
    if (te < 0) return;
    const int e  = te >> 16;
    const int m0 = (te & 0xffff) << 7;
    const int ne = cnt[e];
    const int n0 = blockIdx.x * 64;

    __shared__ __align__(16) unsigned short As[128 * 64];
    __shared__ __align__(16) unsigned short Bs[2][64 * 64];
    __shared__ int rowp[128];

    const int tid = threadIdx.x;
    if (tid < 128) {
        const int slot = m0 + tid;
        rowp[tid] = tok[e * TOKENS + (slot < ne ? slot : ne - 1)];
    }
    __syncthreads();

    const int lane = tid & 63;
    const int w    = tid >> 6;
    const int wm = (w >> 1) * 64;
    const int wn = (w & 1) * 32;
    const int lr = lane & 15;
    const int lq = lane >> 4;

    // ---- A staging: 4 rows/thread, 16B chunk ac, swizzled slot ac^(row&7) ----
    const int ac  = tid & 7;
    const int ar0 = tid >> 3;                 // 0..31
    const unsigned short* asrc0 = xbf + (size_t)(rowp[ar0     ] >> 1) * HIDDEN + ac * 8;
    const unsigned short* asrc1 = xbf + (size_t)(rowp[ar0 + 32] >> 1) * HIDDEN + ac * 8;
    const unsigned short* asrc2 = xbf + (size_t)(rowp[ar0 + 64] >> 1) * HIDDEN + ac * 8;
    const unsigned short* asrc3 = xbf + (size_t)(rowp[ar0 + 96] >> 1) * HIDDEN + ac * 8;
    const int asw = (ac ^ (ar0 & 7)) * 8;     // row&7 identical for all 4 rows
    unsigned short* adst0 = &As[(ar0     ) * 64 + asw];
    unsigned short* adst1 = &As[(ar0 + 32) * 64 + asw];
    unsigned short* adst2 = &As[(ar0 + 64) * 64 + asw];
    unsigned short* adst3 = &As[(ar0 + 96) * 64 + asw];

    // ---- B staging: n=lane, kc = w and w+4; transposed [n][k] with swizzle ----
    const int bn = lane;
    const int bk = w;                          // 0..3
    const float* bsg = wgp + (size_t)e * HIDDEN * INTER + n0 + bn;
    const float* bsu = wup + (size_t)e * HIDDEN * INTER + n0 + bn;
    unsigned short* bdg0 = &Bs[0][bn * 64 + ((bk    ) ^ (bn & 7)) * 8];
    unsigned short* bdg1 = &Bs[0][bn * 64 + ((bk + 4) ^ (bn & 7)) * 8];
    unsigned short* bdu0 = &Bs[1][bn * 64 + ((bk    ) ^ (bn & 7)) * 8];
    unsigned short* bdu1 = &Bs[1][bn * 64 + ((bk + 4) ^ (bn & 7)) * 8];

    f32x4 accg[4][2], accu[4][2];
    const f32x4 z4 = {0.f, 0.f, 0.f, 0.f};
#pragma unroll
    for (int a = 0; a < 4; a++)
#pragma unroll
        for (int b = 0; b < 2; b++) { accg[a][b] = z4; accu[a][b] = z4; }

    uint4 a0, a1, a2, a3;
    f32x8 pgX0, pgX1, puX0, puX1;              // B set X (even steps)
    f32x8 pgY0, pgY1, puY0, puY1;              // B set Y (odd steps)

    // prologue: BX(0) first, then A(0), then BY(1)  (issue order => compiler waits keep BY in flight)
    LOADVEC8(pgX0, bsg, bk * 8,        INTER);
    LOADVEC8(pgX1, bsg, bk * 8 + 32,   INTER);
    LOADVEC8(puX0, bsu, bk * 8,        INTER);
    LOADVEC8(puX1, bsu, bk * 8 + 32,   INTER);
    G_LOADA(0);
    LOADVEC8(pgY0, bsg, BK + bk * 8,        INTER);
    LOADVEC8(pgY1, bsg, BK + bk * 8 + 32,   INTER);
    LOADVEC8(puY0, bsu, BK + bk * 8,        INTER);
    LOADVEC8(puY1, bsu, BK + bk * 8 + 32,   INTER);

#define G1_MFMA_PHASE()                                                           \
    do {                                                                          \
        __builtin_amdgcn_s_setprio(1);                                            \
        _Pragma("unroll")                                                         \
        for (int ks = 0; ks < 2; ks++) {                                          \
            bf16x8 af[4], bg[2], bu[2];                                           \
            _Pragma("unroll")                                                     \
            for (int tm = 0; tm < 4; tm++) {                                      \
                const int r = wm + tm * 16 + lr;                                  \
                af[tm] = *(const bf16x8*)&As[r * 64 + (((ks * 4 + lq) ^ (lr & 7)) * 8)]; \
            }                                                                     \
            _Pragma("unroll")                                                     \
            for (int tn = 0; tn < 2; tn++) {                                      \
                const int r = wn + tn * 16 + lr;                                  \
                const int off = r * 64 + (((ks * 4 + lq) ^ (lr & 7)) * 8);        \
                bg[tn] = *(const bf16x8*)&Bs[0][off];                             \
                bu[tn] = *(const bf16x8*)&Bs[1][off];                             \
            }                                                                     \
            _Pragma("unroll")                                                     \
            for (int tm = 0; tm < 4; tm++)                                        \
                _Pragma("unroll")                                                 \
                for (int tn = 0; tn < 2; tn++) {                                  \
                    accg[tm][tn] = __builtin_amdgcn_mfma_f32_16x16x32_bf16(af[tm], bg[tn], accg[tm][tn], 0, 0, 0); \
                    accu[tm][tn] = __builtin_amdgcn_mfma_f32_16x16x32_bf16(af[tm], bu[tn], accu[tm][tn], 0, 0, 0); \
                }                                                                 \
        }                                                                         \
        __builtin_amdgcn_s_setprio(0);                                            \
    } while (0)

    for (int k0 = 0; k0 < HIDDEN; k0 += 2 * BK) {
        // ======== step even: consume A(k0) + BX(k0) ========
        G_STAGEA();
        cvt_store8(pgX0, bdg0);
        cvt_store8(pgX1, bdg1);
        cvt_store8(puX0, bdu0);
        cvt_store8(puX1, bdu1);
        FENCE_LGKM_BAR();
        G_LOADA(k0 + BK);                       // A for step odd (always valid)
        if (k0 + 2 * BK < HIDDEN) {             // BX for step t+2
            LOADVEC8(pgX0, bsg, k0 + 2 * BK + bk * 8,      INTER);
            LOADVEC8(pgX1, bsg, k0 + 2 * BK + bk * 8 + 32, INTER);
            LOADVEC8(puX0, bsu, k0 + 2 * BK + bk * 8,      INTER);
            LOADVEC8(puX1, bsu, k0 + 2 * BK + bk * 8 + 32, INTER);
        }
        G1_MFMA_PHASE();
        FENCE_BAR2();

        // ======== step odd: consume A(k0+BK) + BY(k0+BK) ========
        G_STAGEA();
        cvt_store8(pgY0, bdg0);
        cvt_store8(pgY1, bdg1);
        cvt_store8(puY0, bdu0);
        cvt_store8(puY1, bdu1);
        FENCE_LGKM_BAR();
        if (k0 + 2 * BK < HIDDEN) G_LOADA(k0 + 2 * BK);
        if (k0 + 3 * BK < HIDDEN) {
            LOADVEC8(pgY0, bsg, k0 + 3 * BK + bk * 8,      INTER);
            LOADVEC8(pgY1, bsg, k0 + 3 * BK + bk * 8 + 32, INTER);
            LOADVEC8(puY0, bsu, k0 + 3 * BK + bk * 8,      INTER);
            LOADVEC8(puY1, bsu, k0 + 3 * BK + bk * 8 + 32, INTER);
        }
        G1_MFMA_PHASE();
        FENCE_BAR2();
    }

    // epilogue: h = silu(g)*u -> bf16, scattered by pair id
#pragma unroll
    for (int tm = 0; tm < 4; tm++)
#pragma unroll
        for (int tn = 0; tn < 2; tn++)
#pragma unroll
            for (int r = 0; r < 4; r++) {
                const int rowL = wm + tm * 16 + lq * 4 + r;
                const int slot = m0 + rowL;
                if (slot < ne) {
                    const int p = rowp[rowL];
                    const int col = n0 + wn + tn * 16 + lr;
                    const float g = accg[tm][tn][r];
                    const float u = accu[tm][tn][r];
                    const float hv = g * u / (1.f + __expf(-g));
                    hbuf[(size_t)p * INTER + col] = bf16bits(hv);
                }
            }
#undef G1_MFMA_PHASE
}

// ---------------- gemm2: out[t] += w * (h_e @ Wd[e]) ----------------
// grid: (HIDDEN/64, MAXTILES), block 256. BM=128 BN=64 BK=64, K=1408.
__global__ __launch_bounds__(256, 2) void gemm2_kernel(
    const unsigned short* __restrict__ hbuf, const float* __restrict__ wdp,
    const int* __restrict__ cnt, const int* __restrict__ tok,
    const float* __restrict__ wts, const int* __restrict__ tiles,
    float* __restrict__ out)
{
    const int te = tiles[blockIdx.y];
    if (te < 0) return;
    const int e  = te >> 16;
    const int m0 = (te & 0xffff) << 7;
    const int ne = cnt[e];
    const int n0 = blockIdx.x * 64;

    __shared__ __align__(16) unsigned short As[128 * 64];
    __shared__ __align__(16) unsigned short Bs[64 * 64];
    __shared__ int rowp[128];
    __shared__ float roww[128];

    const int tid = threadIdx.x;
    if (tid < 128) {
        const int slot = m0 + tid;
        const int cs = slot < ne ? slot : ne - 1;
        rowp[tid] = tok[e * TOKENS + cs];
        roww[tid] = wts[e * TOKENS + cs];
    }
    __syncthreads();

    const int lane = tid & 63;
    const int w    = tid >> 6;
    const int wm = (w >> 1) * 64;
    const int wn = (w & 1) * 32;
    const int lr = lane & 15;
    const int lq = lane >> 4;

    const int ac  = tid & 7;
    const int ar0 = tid >> 3;
    const unsigned short* asrc0 = hbuf + (size_t)rowp[ar0     ] * INTER + ac * 8;
    const unsigned short* asrc1 = hbuf + (size_t)rowp[ar0 + 32] * INTER + ac * 8;
    const unsigned short* asrc2 = hbuf + (size_t)rowp[ar0 + 64] * INTER + ac * 8;
    const unsigned short* asrc3 = hbuf + (size_t)rowp[ar0 + 96] * INTER + ac * 8;
    const int asw = (ac ^ (ar0 & 7)) * 8;
    unsigned short* adst0 = &As[(ar0     ) * 64 + asw];
    unsigned short* adst1 = &As[(ar0 + 32) * 64 + asw];
    unsigned short* adst2 = &As[(ar0 + 64) * 64 + asw];
    unsigned short* adst3 = &As[(ar0 + 96) * 64 + asw];

    const int bn = lane;
    const int bk = w;
    const float* bsd = wdp + (size_t)e * INTER * HIDDEN + n0 + bn;
    unsigned short* bdd0 = &Bs[bn * 64 + ((bk    ) ^ (bn & 7)) * 8];
    unsigned short* bdd1 = &Bs[bn * 64 + ((bk + 4) ^ (bn & 7)) * 8];

    f32x4 acc[4][2];
    const f32x4 z4 = {0.f, 0.f, 0.f, 0.f};
#pragma unroll
    for (int a = 0; a < 4; a++)
#pragma unroll
        for (int b = 0; b < 2; b++) acc[a][b] = z4;

    uint4 a0, a1, a2, a3;
    f32x8 pdX0, pdX1, pdY0, pdY1;

    // prologue: BX(0), A(0), BY(1)
    LOADVEC8(pdX0, bsd, bk * 8,      HIDDEN);
    LOADVEC8(pdX1, bsd, bk * 8 + 32, HIDDEN);
    G_LOADA(0);
    LOADVEC8(pdY0, bsd, BK + bk * 8,      HIDDEN);
    LOADVEC8(pdY1, bsd, BK + bk * 8 + 32, HIDDEN);

#define G2_MFMA_PHASE()                                                           \
    do {                                                                          \
        __builtin_amdgcn_s_setprio(1);                                            \
        _Pragma("unroll")                                                         \
        for (int ks = 0; ks < 2; ks++) {                                          \
            bf16x8 af[4], bb[2];                                                  \
            _Pragma("unroll")                                                     \
            for (int tm = 0; tm < 4; tm++) {                                      \
                const int r = wm + tm * 16 + lr;                                  \
                af[tm] = *(const bf16x8*)&As[r * 64 + (((ks * 4 + lq) ^ (lr & 7)) * 8)]; \
            }                                                                     \
            _Pragma("unroll")                                                     \
            for (int tn = 0; tn < 2; tn++) {                                      \
                const int r = wn + tn * 16 + lr;                                  \
                bb[tn] = *(const bf16x8*)&Bs[r * 64 + (((ks * 4 + lq) ^ (lr & 7)) * 8)]; \
            }                                                                     \
            _Pragma("unroll")                                                     \
            for (int tm = 0; tm < 4; tm++)                                        \
                _Pragma("unroll")                                                 \
                for (int tn = 0; tn < 2; tn++)                                    \
                    acc[tm][tn] = __builtin_amdgcn_mfma_f32_16x16x32_bf16(af[tm], bb[tn], acc[tm][tn], 0, 0, 0); \
        }                                                                         \
        __builtin_amdgcn_s_setprio(0);                                            \
    } while (0)

    for (int k0 = 0; k0 < INTER; k0 += 2 * BK) {
        // ======== step even ========
        G_STAGEA();
        cvt_store8(pdX0, bdd0);
        cvt_store8(pdX1, bdd1);
        FENCE_LGKM_BAR();
        G_LOADA(k0 + BK);                       // always valid (1344 < 1408)
        if (k0 + 2 * BK < INTER) {
            LOADVEC8(pdX0, bsd, k0 + 2 * BK + bk * 8,      HIDDEN);
            LOADVEC8(pdX1, bsd, k0 + 2 * BK + bk * 8 + 32, HIDDEN);
        }
        G2_MFMA_PHASE();
        FENCE_BAR2();

        // ======== step odd ========
        G_STAGEA();
        cvt_store8(pdY0, bdd0);
        cvt_store8(pdY1, bdd1);
        FENCE_LGKM_BAR();
        if (k0 + 2 * BK < INTER) G_LOADA(k0 + 2 * BK);
        if (k0 + 3 * BK < INTER) {
            LOADVEC8(pdY0, bsd, k0 + 3 * BK + bk * 8,      HIDDEN);
            LOADVEC8(pdY1, bsd, k0 + 3 * BK + bk * 8 + 32, HIDDEN);
        }
        G2_MFMA_PHASE();
        FENCE_BAR2();
    }

#pragma unroll
    for (int tm = 0; tm < 4; tm++)
#pragma unroll
        for (int tn = 0; tn < 2; tn++)
#pragma unroll
            for (int r = 0; r < 4; r++) {
                const int rowL = wm + tm * 16 + lq * 4 + r;
                const int slot = m0 + rowL;
                if (slot < ne) {
                    const int t = rowp[rowL] >> 1;
                    const float wv = roww[rowL];
                    atomicAdd(&out[(size_t)t * HIDDEN + n0 + wn + tn * 16 + lr],
                              wv * acc[tm][tn][r]);
                }
            }
#undef G2_MFMA_PHASE
}

extern "C" void kernel_launch(void* const* d_in, const int* in_sizes, int n_in,
                              void* d_out, int out_size, void* d_ws, size_t ws_size,
                              hipStream_t stream) {
    const float* x   = (const float*)d_in[0];
    const float* wg  = (const float*)d_in[1];
    const float* wgp = (const float*)d_in[2];
    const float* wup = (const float*)d_in[3];
    const float* wdp = (const float*)d_in[4];
    float* out = (float*)d_out;

    char* ws = (char*)d_ws;
    int*   cnt   = (int*)ws;                             // 64 B
    int*   tiles = (int*)(ws + 64);                      // 48*4 = 192 B (ends at 256)
    int*   tok  = (int*)(ws + 256);                      // 16*2048*4 = 131072
    float* wts  = (float*)(ws + 256 + 131072);           // 131072
    unsigned short* xbf  = (unsigned short*)(ws + 262400);            // 2048*2048*2 = 8 MB
    unsigned short* hbuf = (unsigned short*)(ws + 262400 + 8388608);  // 4096*1408*2 = 11.5 MB

    hipMemsetAsync(cnt, 0, NEXP * sizeof(int), stream);
    hipMemsetAsync(out, 0, (size_t)TOKENS * HIDDEN * sizeof(float), stream);

    router_kernel<<<dim3(TOKENS), dim3(64), 0, stream>>>(x, wg, cnt, tok, wts, xbf);

    schedule_kernel<<<dim3(1), dim3(64), 0, stream>>>(cnt, tiles);

    dim3 g1(INTER / 64, MAXTILES);    // (22, 48), all-y compacted tile list
    gemm1_kernel<<<g1, dim3(256), 0, stream>>>(xbf, wgp, wup, cnt, tok, tiles, hbuf);

    dim3 g2(HIDDEN / 64, MAXTILES);   // (32, 48)
    gemm2_kernel<<<g2, dim3(256), 0, stream>>>(hbuf, wdp, cnt, tok, wts, tiles, out);
}